// Round 10
// baseline (2505.318 us; speedup 1.0000x reference)
//
#include <hip/hip_runtime.h>
#include <hip/hip_bf16.h>

// Problem constants
#define B_    32
#define S_    512
#define E_    512
#define H_    1024          // U_DIM
#define G4_   4096          // 4*U_DIM
#define NSB_  32            // scan blocks (512 thr: 8 waves)
#define NGB_  224           // gemm worker blocks (512 thr)
#define HPAD_ 1048          // Hs row stride bytes

typedef __attribute__((ext_vector_type(8))) short short8;
typedef __attribute__((ext_vector_type(4))) float f32x4;
typedef unsigned long long u64;

__device__ __forceinline__ float bf2f(ushort u) {
    union { unsigned u32; float f; } cv; cv.u32 = ((unsigned)u) << 16; return cv.f;
}
__device__ __forceinline__ ushort f2bf(float f) {
    union { float f; unsigned u; } cv; cv.f = f;
    unsigned u = cv.u;
    u += 0x7FFFu + ((u >> 16) & 1u);   // RNE
    return (ushort)(u >> 16);
}
__device__ __forceinline__ float tanh_fast(float x) {
    float e = __builtin_amdgcn_exp2f(x * 2.885390081777927f);
    return 1.0f - 2.0f * __builtin_amdgcn_rcpf(e + 1.0f);
}

// ---------------- init: zero h0 tags, cnt, build per-step row masks ----------------
__global__ void init_kernel(const int* __restrict__ tokens, u64* hA, unsigned* cnt,
                            unsigned* __restrict__ m32) {
    int i = blockIdx.x * 256 + threadIdx.x;   // grid 16x256 -> 0..4095
    hA[i] = 0ull; hA[i + 4096] = 0ull;        // hA fully zeroed (tag 0); hB overwritten at t=0
    if (i < 128) cnt[i] = 0u;
    if (i < 512) {
        unsigned m = 0;
        for (int b = 0; b < 32; ++b)
            m |= (tokens[b * S_ + i] != 0 ? 1u : 0u) << b;
        m32[i] = m;
    }
}

// ---------------- W transpose: fp32 [E][G4] -> bf16 WT[n][k] ----------------
__global__ void transpose_w_kernel(const float* __restrict__ src, ushort* __restrict__ dst) {
    __shared__ float tile[32][33];
    int kx = blockIdx.y * 32;
    int nx = blockIdx.x * 32;
    int c  = threadIdx.x & 31;
    int r0 = threadIdx.x >> 5;
    for (int rr = r0; rr < 32; rr += 8)
        tile[rr][c] = src[(size_t)(kx + rr) * G4_ + nx + c];
    __syncthreads();
    for (int rr = r0; rr < 32; rr += 8)
        dst[(size_t)(nx + rr) * E_ + kx + c] = f2bf(tile[c][rr]);
}

// ---------------- U transpose: fp32 [H][G4] -> fp8(e4m3, x64) UT[n'][k], n'=j*4+g ----------------
__global__ void transpose_u_kernel(const float* __restrict__ src, unsigned* __restrict__ dst) {
    __shared__ float tile[32][33];
    int kx = blockIdx.y * 32;
    int nx = blockIdx.x * 32;
    int c  = threadIdx.x & 31;
    int r0 = threadIdx.x >> 5;
    for (int rr = r0; rr < 32; rr += 8)
        tile[rr][c] = src[(size_t)(kx + rr) * G4_ + nx + c];
    __syncthreads();
    int r  = threadIdx.x >> 3;    // n-index in tile 0..31
    int c3 = threadIdx.x & 7;     // k-quad
    int n  = nx + r;
    int np = (n & 1023) * 4 + (n >> 10);
    float v0 = tile[c3 * 4 + 0][r] * 64.0f;
    float v1 = tile[c3 * 4 + 1][r] * 64.0f;
    float v2 = tile[c3 * 4 + 2][r] * 64.0f;
    float v3 = tile[c3 * 4 + 3][r] * 64.0f;
    int pk = __builtin_amdgcn_cvt_pk_fp8_f32(v0, v1, 0, false);
    pk     = __builtin_amdgcn_cvt_pk_fp8_f32(v2, v3, pk, true);
    dst[((size_t)np * H_ + kx + c3 * 4) >> 2] = (unsigned)pk;
}

// ---------------- mono kernel: 32 scan blocks + 224 gemm workers, all 512 thr ----------------
// Scan computes z^T = U . h^T: all 4 gates of one (b,j) land in one lane's acc regs.
// xWT layout [t][b][n'] (u64 = 4 gates of one j). GEMM epilogue stores u64 direct.
__global__ __launch_bounds__(512, 1) void mono_kernel(
    const unsigned char* __restrict__ UT,  // fp8 [4096][1024]
    u64* xWT,                              // bf16 [512][32][4096] as u64 (workers write)
    const unsigned* __restrict__ m32,      // [512] row masks
    u64* hA, u64* hB,                      // tagged h chunks [32][256] ping-pong
    unsigned* cnt,                         // [128] per-t-quad completion counters
    float* __restrict__ out,               // [3][32][1024] fp32
    const int* __restrict__ tokens,
    const float* __restrict__ emb,
    const ushort* __restrict__ WT,         // bf16 [4096][512]
    const float* __restrict__ bias) {
    __shared__ u64 smem[4192];             // scan: Hs 33.5 KB (gemm path unused)

    const int tid  = threadIdx.x;
    const int lane = tid & 63;
    const int w    = tid >> 6;            // 0..7
    const int lr = lane & 15, lq = lane >> 4;

    if (blockIdx.x >= NSB_) {
        // ================= GEMM worker (8 waves: 4 t x 2 row-halves) =================
        const int blkg = blockIdx.x - NSB_;
        for (int u = blkg; u < 4096; u += NGB_) {
            const int mb = u >> 5, jb = u & 31;
            const int t    = mb * 4 + (w >> 1);
            const int brow = (w & 1) * 16 + lr;     // batch row
            const int tok  = tokens[brow * S_ + t];
            const float* arow = emb + (size_t)tok * E_;

            f32x4 acc[8] = {{0,0,0,0},{0,0,0,0},{0,0,0,0},{0,0,0,0},
                            {0,0,0,0},{0,0,0,0},{0,0,0,0},{0,0,0,0}};
            #pragma unroll 2
            for (int ks = 0; ks < E_ / 32; ++ks) {
                const float* ap = arow + ks * 32 + lq * 8;
                float4 a0 = *reinterpret_cast<const float4*>(ap);
                float4 a1 = *reinterpret_cast<const float4*>(ap + 4);
                short8 af;
                af[0] = (short)f2bf(a0.x); af[1] = (short)f2bf(a0.y);
                af[2] = (short)f2bf(a0.z); af[3] = (short)f2bf(a0.w);
                af[4] = (short)f2bf(a1.x); af[5] = (short)f2bf(a1.y);
                af[6] = (short)f2bf(a1.z); af[7] = (short)f2bf(a1.w);
                #pragma unroll
                for (int s = 0; s < 4; ++s)
                    #pragma unroll
                    for (int h = 0; h < 2; ++h) {
                        const ushort* bp = WT + (size_t)(s * 1024 + jb * 32 + h * 16 + lr) * E_;
                        short8 bf = *reinterpret_cast<const short8*>(bp + ks * 32 + lq * 8);
                        acc[s * 2 + h] = __builtin_amdgcn_mfma_f32_16x16x32_bf16(af, bf, acc[s * 2 + h], 0, 0, 0);
                    }
            }
            // epilogue: pack over s (4 gates of one j) -> u64, store direct [t][b][j]
            #pragma unroll
            for (int h = 0; h < 2; ++h) {
                int j = jb * 32 + h * 16 + lr;       // global j
                float bv[4];
                #pragma unroll
                for (int s = 0; s < 4; ++s) bv[s] = bias[s * 1024 + j];
                #pragma unroll
                for (int r = 0; r < 4; ++r) {
                    int b = (w & 1) * 16 + lq * 4 + r;   // batch (C row)
                    u64 pk = 0;
                    #pragma unroll
                    for (int s = 0; s < 4; ++s)
                        pk |= (u64)f2bf(acc[s * 2 + h][r] + bv[s]) << (16 * s);
                    __hip_atomic_store(xWT + ((size_t)t * B_ + b) * 1024 + j, pk,
                                       __ATOMIC_RELAXED, __HIP_MEMORY_SCOPE_AGENT);
                }
            }
            __syncthreads();                     // drains all waves' stores (vmcnt 0)
            if (tid == 0)
                __hip_atomic_fetch_add(&cnt[mb], 1u, __ATOMIC_RELAXED, __HIP_MEMORY_SCOPE_AGENT);
        }
        return;
    }

    // ================= persistent LSTM scan (z^T orientation) =================
    unsigned char* Hs = (unsigned char*)smem;
    const int blk  = blockIdx.x;
    const int nb  = blk * 128 + w * 16;   // wave's n' base (16 n' = 4 j)
    const int jw  = nb >> 2;              // wave's j base
    const int jme = jw + lq;              // this lane's j
    const int cw  = blk * 8 + w;          // chunk col (u64 of 4 j) this wave produces

    // step-invariant A fragments (U slice): lane (m=lr -> n'=nb+lr, kq=lq)
    u64 ub[32];
    #pragma unroll
    for (int ks = 0; ks < 32; ++ks)
        ub[ks] = *reinterpret_cast<const u64*>(UT + (size_t)(nb + lr) * H_ + ks * 32 + lq * 8);
    #pragma unroll
    for (int ks = 0; ks < 32; ++ks)
        asm volatile("" : "+v"(ub[ks]));

    float c0 = 0.f, h0 = 0.f;             // state for (b=lr,    j=jme)
    float c1 = 0.f, h1 = 0.f;             // state for (b=16+lr, j=jme)

    const u64* hcur = hA;
    u64*       hnxt = hB;

    // wait for xW slice mb=0 (t=0..3), then load t=0 inputs
    while (__hip_atomic_load(&cnt[0], __ATOMIC_RELAXED, __HIP_MEMORY_SCOPE_AGENT) < 32u)
        __builtin_amdgcn_s_sleep(8);
    asm volatile("" ::: "memory");
    u64 xwv0 = xWT[((size_t)0 * B_ + lr) * 1024 + jme];
    u64 xwv1 = xWT[((size_t)0 * B_ + 16 + lr) * 1024 + jme];
    unsigned mask = m32[0];
    int mb_conf = 1;
    unsigned cv = __hip_atomic_load(&cnt[1], __ATOMIC_RELAXED, __HIP_MEMORY_SCOPE_AGENT);

    for (int t = 0; t < S_; ++t) {
        // ---- poll+stage: unconditional pipelined 16-load bursts until all tags fresh ----
        {
            const unsigned tv = (unsigned)t;
            u64 hv[16];
            for (;;) {
                #pragma unroll
                for (int i = 0; i < 16; ++i)
                    hv[i] = __hip_atomic_load(hcur + tid + i * 512,
                                              __ATOMIC_RELAXED, __HIP_MEMORY_SCOPE_AGENT);
                unsigned bad = 0u;
                #pragma unroll
                for (int i = 0; i < 16; ++i)
                    bad |= ((unsigned)(hv[i] >> 32)) ^ tv;
                if (__all(bad == 0u)) break;
                __builtin_amdgcn_s_sleep(1);
            }
            #pragma unroll
            for (int i = 0; i < 16; ++i) {
                int e = tid + i * 512, row = e >> 8, kc = e & 255;
                *reinterpret_cast<unsigned*>(&Hs[row * HPAD_ + kc * 4]) = (unsigned)hv[i];
            }
        }
        __syncthreads();

        // ---- z^T tiles = U . h^T (fp8 MFMA, K=1024; shared A=U, B=h rows) ----
        f32x4 acc0 = {0,0,0,0}, acc1 = {0,0,0,0};
        #pragma unroll
        for (int ks = 0; ks < 32; ++ks) {
            u64 bf0 = *reinterpret_cast<const u64*>(&Hs[lr * HPAD_ + ks * 32 + lq * 8]);
            u64 bf1 = *reinterpret_cast<const u64*>(&Hs[(16 + lr) * HPAD_ + ks * 32 + lq * 8]);
            acc0 = __builtin_amdgcn_mfma_f32_16x16x32_fp8_fp8((long)ub[ks], (long)bf0, acc0, 0, 0, 0);
            acc1 = __builtin_amdgcn_mfma_f32_16x16x32_fp8_fp8((long)ub[ks], (long)bf1, acc1, 0, 0, 0);
        }

        // ---- gates: all 4 gates of (b,jme) are local acc regs; no cross-lane ----
        const bool notlast = (t < S_ - 1);
        {
            float ti = tanh_fast(acc0[0] * (1.0f / 16384.0f) + bf2f((ushort)(xwv0)));
            float tf = tanh_fast(acc0[1] * (1.0f / 16384.0f) + bf2f((ushort)(xwv0 >> 16)));
            float tg = tanh_fast(acc0[2] * (1.0f / 16384.0f) + bf2f((ushort)(xwv0 >> 32)));
            float to = tanh_fast(acc0[3] * (1.0f / 16384.0f) + bf2f((ushort)(xwv0 >> 48)));
            float cn = tf * c0 + ti * tg;
            float hn = to * tanh_fast(cn);
            if ((mask >> lr) & 1) { c0 = cn; h0 = hn; }
        }
        {
            float ti = tanh_fast(acc1[0] * (1.0f / 16384.0f) + bf2f((ushort)(xwv1)));
            float tf = tanh_fast(acc1[1] * (1.0f / 16384.0f) + bf2f((ushort)(xwv1 >> 16)));
            float tg = tanh_fast(acc1[2] * (1.0f / 16384.0f) + bf2f((ushort)(xwv1 >> 32)));
            float to = tanh_fast(acc1[3] * (1.0f / 16384.0f) + bf2f((ushort)(xwv1 >> 48)));
            float cn = tf * c1 + ti * tg;
            float hn = to * tanh_fast(cn);
            if ((mask >> (16 + lr)) & 1) { c1 = cn; h1 = hn; }
        }

        if (notlast) {
            // ---- pack 4 j (lq lanes) -> u32 fp8 (x256), 2 shfl per tile; store on lq==0 ----
            const u64 tagw = (u64)(unsigned)(t + 1) << 32;
            {
                float a = h0 * 256.0f;
                float bx = __shfl_xor(a, 16, 64);           // partner j (lq^1)
                int lo = __builtin_amdgcn_cvt_pk_fp8_f32(a, bx, 0, false);  // (j_lq, j_lq^1)
                int hi = __shfl_xor(lo, 32, 64);            // (j2,j3) for lq=0
                unsigned pk = ((unsigned)lo & 0xFFFFu) | ((unsigned)hi << 16);
                if (lq == 0)
                    __hip_atomic_store(hnxt + lr * 256 + cw, (u64)pk | tagw,
                                       __ATOMIC_RELAXED, __HIP_MEMORY_SCOPE_AGENT);
            }
            {
                float a = h1 * 256.0f;
                float bx = __shfl_xor(a, 16, 64);
                int lo = __builtin_amdgcn_cvt_pk_fp8_f32(a, bx, 0, false);
                int hi = __shfl_xor(lo, 32, 64);
                unsigned pk = ((unsigned)lo & 0xFFFFu) | ((unsigned)hi << 16);
                if (lq == 0)
                    __hip_atomic_store(hnxt + (16 + lr) * 256 + cw, (u64)pk | tagw,
                                       __ATOMIC_RELAXED, __HIP_MEMORY_SCOPE_AGENT);
            }
            // ---- gate xw prefetch on gemm completion (pipelined: register compare) ----
            int mbn = (t + 1) >> 2;
            if (mbn >= mb_conf) {
                while (cv < 32u) {
                    __builtin_amdgcn_s_sleep(4);
                    cv = __hip_atomic_load(&cnt[mbn], __ATOMIC_RELAXED, __HIP_MEMORY_SCOPE_AGENT);
                }
                mb_conf = mbn + 1;
                int nx = mbn + 1 < 128 ? mbn + 1 : 127;
                cv = __hip_atomic_load(&cnt[nx], __ATOMIC_RELAXED, __HIP_MEMORY_SCOPE_AGENT);
                asm volatile("" ::: "memory");
            }
            xwv0 = xWT[((size_t)(t + 1) * B_ + lr) * 1024 + jme];
            xwv1 = xWT[((size_t)(t + 1) * B_ + 16 + lr) * 1024 + jme];
            mask = m32[t + 1];
            const u64* tsw = hcur; hcur = hnxt; hnxt = (u64*)tsw;
        } else {
            // ---- final: write (h, h, c) fp32 — every lane owns (b, jme) pairs ----
            out[lr * H_ + jme]                      = h0;
            out[B_ * H_ + lr * H_ + jme]            = h0;
            out[2 * B_ * H_ + lr * H_ + jme]        = c0;
            out[(16 + lr) * H_ + jme]               = h1;
            out[B_ * H_ + (16 + lr) * H_ + jme]     = h1;
            out[2 * B_ * H_ + (16 + lr) * H_ + jme] = c1;
        }
    }
}

extern "C" void kernel_launch(void* const* d_in, const int* in_sizes, int n_in,
                              void* d_out, int out_size, void* d_ws, size_t ws_size,
                              hipStream_t stream) {
    (void)in_sizes; (void)n_in; (void)out_size; (void)ws_size;
    const int*   tokens = (const int*)  d_in[0];
    const float* emb    = (const float*)d_in[1];
    const float* W      = (const float*)d_in[2];
    const float* U      = (const float*)d_in[3];
    const float* bias   = (const float*)d_in[4];

    char* ws = (char*)d_ws;
    ushort*        WT   = (ushort*)ws;                               // 4 MB
    unsigned char* UT   = (unsigned char*)(ws + (4u << 20));         // 4 MB fp8
    u64*           xWT  = (u64*)(ws + (8u << 20));                   // 128 MB [t][b][j]
    u64*           hA   = (u64*)(ws + (136u << 20));                 // 64 KB tagged
    u64*           hB   = hA + 8192;                                 // 64 KB tagged
    unsigned*      m32  = (unsigned*)(hB + 8192);                    // 2 KB
    unsigned*      cnt  = m32 + 512;                                 // 512 B

    init_kernel<<<16, 256, 0, stream>>>(tokens, hA, cnt, m32);
    transpose_w_kernel<<<dim3(G4_ / 32, E_ / 32), 256, 0, stream>>>(W, WT);
    transpose_u_kernel<<<dim3(G4_ / 32, H_ / 32), 256, 0, stream>>>(U, (unsigned*)UT);
    mono_kernel<<<NSB_ + NGB_, 512, 0, stream>>>(UT, xWT, m32, hA, hB, cnt, (float*)d_out,
                                                 tokens, emb, WT, bias);
}

// Round 12
// 1896.112 us; speedup vs baseline: 1.3213x; 1.3213x over previous
//
#include <hip/hip_runtime.h>
#include <hip/hip_bf16.h>

// Problem constants
#define B_    32
#define S_    512
#define E_    512
#define H_    1024          // U_DIM
#define G4_   4096          // 4*U_DIM
#define NSB_  64            // scan blocks: 2 independent halves x 32 blocks
#define NGB_  192           // gemm worker blocks
#define HPAD_ 1048          // Hs row stride bytes

typedef __attribute__((ext_vector_type(8))) short short8;
typedef __attribute__((ext_vector_type(4))) float f32x4;
typedef unsigned long long u64;

__device__ __forceinline__ float bf2f(ushort u) {
    union { unsigned u32; float f; } cv; cv.u32 = ((unsigned)u) << 16; return cv.f;
}
__device__ __forceinline__ ushort f2bf(float f) {
    union { float f; unsigned u; } cv; cv.f = f;
    unsigned u = cv.u;
    u += 0x7FFFu + ((u >> 16) & 1u);   // RNE
    return (ushort)(u >> 16);
}
__device__ __forceinline__ float tanh_fast(float x) {
    float e = __builtin_amdgcn_exp2f(x * 2.885390081777927f);
    return 1.0f - 2.0f * __builtin_amdgcn_rcpf(e + 1.0f);
}
__device__ __forceinline__ float sel4(int s, float a0, float a1, float a2, float a3) {
    return (s & 2) ? ((s & 1) ? a3 : a2) : ((s & 1) ? a1 : a0);
}

// ---------------- init: zero h0 tags, cnt, build per-step row masks ----------------
__global__ void init_kernel(const int* __restrict__ tokens, u64* hA, unsigned* cnt,
                            unsigned* __restrict__ m32) {
    int i = blockIdx.x * 256 + threadIdx.x;   // grid 16x256 -> 0..4095
    hA[i] = 0ull; hA[i + 4096] = 0ull;        // hA fully zeroed (tag 0)
    if (i < 256) cnt[i] = 0u;
    if (i < 512) {
        unsigned m = 0;
        for (int b = 0; b < 32; ++b)
            m |= (tokens[b * S_ + i] != 0 ? 1u : 0u) << b;
        m32[i] = m;
    }
}

// ---------------- W transpose: fp32 [E][G4] -> bf16 WT[n][k] ----------------
__global__ void transpose_w_kernel(const float* __restrict__ src, ushort* __restrict__ dst) {
    __shared__ float tile[32][33];
    int kx = blockIdx.y * 32;
    int nx = blockIdx.x * 32;
    int c  = threadIdx.x & 31;
    int r0 = threadIdx.x >> 5;
    for (int rr = r0; rr < 32; rr += 8)
        tile[rr][c] = src[(size_t)(kx + rr) * G4_ + nx + c];
    __syncthreads();
    for (int rr = r0; rr < 32; rr += 8)
        dst[(size_t)(nx + rr) * E_ + kx + c] = f2bf(tile[c][rr]);
}

// ---------------- U transpose: fp32 [H][G4] -> fp8(e4m3, x64) UT[n'][k], n'=j*4+g ----------------
__global__ void transpose_u_kernel(const float* __restrict__ src, unsigned* __restrict__ dst) {
    __shared__ float tile[32][33];
    int kx = blockIdx.y * 32;
    int nx = blockIdx.x * 32;
    int c  = threadIdx.x & 31;
    int r0 = threadIdx.x >> 5;
    for (int rr = r0; rr < 32; rr += 8)
        tile[rr][c] = src[(size_t)(kx + rr) * G4_ + nx + c];
    __syncthreads();
    int r  = threadIdx.x >> 3;    // n-index in tile 0..31
    int c3 = threadIdx.x & 7;     // k-quad
    int n  = nx + r;
    int np = (n & 1023) * 4 + (n >> 10);
    float v0 = tile[c3 * 4 + 0][r] * 64.0f;
    float v1 = tile[c3 * 4 + 1][r] * 64.0f;
    float v2 = tile[c3 * 4 + 2][r] * 64.0f;
    float v3 = tile[c3 * 4 + 3][r] * 64.0f;
    int pk = __builtin_amdgcn_cvt_pk_fp8_f32(v0, v1, 0, false);
    pk     = __builtin_amdgcn_cvt_pk_fp8_f32(v2, v3, pk, true);
    dst[((size_t)np * H_ + kx + c3 * 4) >> 2] = (unsigned)pk;
}

// ---------------- mono kernel: 64 scan blocks (2 indep. halves) + 192 gemm workers ----------------
// Batch rows are independent in the recurrence -> split into 2 sync domains of 32
// blocks (batch 0-15 / 16-31). Each block: 16 rows x 128 n'-cols, polls 32 KB.
__global__ __launch_bounds__(256, 1) void mono_kernel(
    const unsigned char* __restrict__ UT,  // fp8 [4096][1024]
    ushort* xWT,                           // bf16 [512][4096][32] (workers write, scan reads)
    const unsigned* __restrict__ m32,      // [512] row masks
    u64* hA, u64* hB,                      // tagged h chunks [32][256] ping-pong
    unsigned* cnt,                         // [256] per-t-pair completion counters
    float* __restrict__ out,               // [3][32][1024] fp32
    const int* __restrict__ tokens,
    const float* __restrict__ emb,
    const ushort* __restrict__ WT,         // bf16 [4096][512]
    const float* __restrict__ bias) {
    __shared__ u64 smem[2112];             // scan: Hs 16.8 KB | gemm: Cs 16 KB

    const int tid  = threadIdx.x;
    const int lane = tid & 63;
    const int w    = tid >> 6;            // 0..3
    const int lr = lane & 15, lq = lane >> 4;

    if (blockIdx.x >= NSB_) {
        // ================= GEMM worker (R8 core) =================
        const int blkg = blockIdx.x - NSB_;
        u64* Cs = smem;                    // [tp2][npl128][b4 8] u64 = 2048
        for (int u = blkg; u < 8192; u += NGB_) {
            const int mb = u >> 5, jb = u & 31;
            const int t    = mb * 2 + (w >> 1);
            const int brow = (w & 1) * 16 + lr;
            const int tok  = tokens[brow * S_ + t];
            const float* arow = emb + (size_t)tok * E_;

            f32x4 acc[8] = {{0,0,0,0},{0,0,0,0},{0,0,0,0},{0,0,0,0},
                            {0,0,0,0},{0,0,0,0},{0,0,0,0},{0,0,0,0}};
            #pragma unroll 2
            for (int ks = 0; ks < E_ / 32; ++ks) {
                const float* ap = arow + ks * 32 + lq * 8;
                float4 a0 = *reinterpret_cast<const float4*>(ap);
                float4 a1 = *reinterpret_cast<const float4*>(ap + 4);
                short8 af;
                af[0] = (short)f2bf(a0.x); af[1] = (short)f2bf(a0.y);
                af[2] = (short)f2bf(a0.z); af[3] = (short)f2bf(a0.w);
                af[4] = (short)f2bf(a1.x); af[5] = (short)f2bf(a1.y);
                af[6] = (short)f2bf(a1.z); af[7] = (short)f2bf(a1.w);
                #pragma unroll
                for (int s = 0; s < 4; ++s)
                    #pragma unroll
                    for (int h = 0; h < 2; ++h) {
                        const ushort* bp = WT + (size_t)(s * 1024 + jb * 32 + h * 16 + lr) * E_;
                        short8 bf = *reinterpret_cast<const short8*>(bp + ks * 32 + lq * 8);
                        acc[s * 2 + h] = __builtin_amdgcn_mfma_f32_16x16x32_bf16(af, bf, acc[s * 2 + h], 0, 0, 0);
                    }
            }
            #pragma unroll
            for (int s = 0; s < 4; ++s)
                #pragma unroll
                for (int h = 0; h < 2; ++h) {
                    int n = s * 1024 + jb * 32 + h * 16 + lr;
                    float bv = bias[n];
                    u64 pk = 0;
                    #pragma unroll
                    for (int r = 0; r < 4; ++r)
                        pk |= (u64)f2bf(acc[s * 2 + h][r] + bv) << (16 * r);
                    int npl = (h * 16 + lr) * 4 + s;             // 0..127
                    Cs[((size_t)(w >> 1) * 128 + npl) * 8 + (w & 1) * 4 + lq] = pk;
                }
            __syncthreads();
            #pragma unroll
            for (int i = 0; i < 8; ++i) {
                int e   = tid + i * 256;         // 0..2047 (FULL Cs tile; R11 bug was i<4)
                int tp  = e >> 10;
                int rem = e & 1023;
                u64* dst = (u64*)(xWT + ((size_t)(mb * 2 + tp) * G4_ + jb * 128) * B_) + rem;
                __hip_atomic_store(dst, Cs[e], __ATOMIC_RELAXED, __HIP_MEMORY_SCOPE_AGENT);
            }
            __syncthreads();                     // drains all waves' stores (vmcnt 0)
            if (tid == 0)
                __hip_atomic_fetch_add(&cnt[mb], 1u, __ATOMIC_RELAXED, __HIP_MEMORY_SCOPE_AGENT);
        }
        return;
    }

    // ================= persistent LSTM scan: half-domain (16 batch rows) =================
    unsigned char* Hs = (unsigned char*)smem;   // 16 rows x HPAD_
    const int blk  = blockIdx.x;
    const int half = blk >> 5;            // 0: batch 0-15, 1: batch 16-31
    const int bq   = blk & 31;            // n'-block within half
    const int m0   = half * 16;           // global batch base (block-uniform)
    const int n0 = bq * 128 + w * 32;
    const int c0 = n0 + lr;               // tile0 global n'
    const int c1 = n0 + 16 + lr;          // tile1 global n'
    const int g  = lr & 3;                // gate id
    const int cb = bq * 8 + w * 2;        // chunk col base (units of 4 j)
    const int rowbase = half * 16;        // chunk row base

    // step-invariant B fragments -> pinned regs
    u64 ub0[32], ub1[32];
    #pragma unroll
    for (int ks = 0; ks < 32; ++ks) {
        ub0[ks] = *reinterpret_cast<const u64*>(UT + (size_t)c0 * H_ + ks * 32 + lq * 8);
        ub1[ks] = *reinterpret_cast<const u64*>(UT + (size_t)c1 * H_ + ks * 32 + lq * 8);
    }
    #pragma unroll
    for (int ks = 0; ks < 32; ++ks) {
        asm volatile("" : "+v"(ub0[ks]));
        asm volatile("" : "+v"(ub1[ks]));
    }

    float creg0[4] = {0,0,0,0}, hreg0[4] = {0,0,0,0};
    float creg1[4] = {0,0,0,0}, hreg1[4] = {0,0,0,0};

    const u64* hcur = hA;
    u64*       hnxt = hB;

    // wait for xW slice mb=0 (t=0,1), then load t=0 inputs
    while (__hip_atomic_load(&cnt[0], __ATOMIC_RELAXED, __HIP_MEMORY_SCOPE_AGENT) < 32u)
        __builtin_amdgcn_s_sleep(8);
    asm volatile("" ::: "memory");
    u64 xwv0 = *reinterpret_cast<const u64*>(xWT + ((size_t)0 * G4_ + c0) * B_ + m0 + lq * 4);
    u64 xwv1 = *reinterpret_cast<const u64*>(xWT + ((size_t)0 * G4_ + c1) * B_ + m0 + lq * 4);
    unsigned mask = m32[0];
    int mb_conf = 1;                       // cnt[0] confirmed
    unsigned cv = __hip_atomic_load(&cnt[1], __ATOMIC_RELAXED, __HIP_MEMORY_SCOPE_AGENT);

    for (int t = 0; t < S_; ++t) {
        // ---- poll+stage: this half's 4096 chunks only (16 loads x 256 thr) ----
        {
            const unsigned tv = (unsigned)t;
            u64 hv[16];
            for (;;) {
                #pragma unroll
                for (int i = 0; i < 16; ++i)
                    hv[i] = __hip_atomic_load(hcur + (size_t)(rowbase + i) * 256 + tid,
                                              __ATOMIC_RELAXED, __HIP_MEMORY_SCOPE_AGENT);
                unsigned bad = 0u;
                #pragma unroll
                for (int i = 0; i < 16; ++i)
                    bad |= ((unsigned)(hv[i] >> 32)) ^ tv;
                if (__all(bad == 0u)) break;
                __builtin_amdgcn_s_sleep(1);
            }
            #pragma unroll
            for (int i = 0; i < 16; ++i)
                *reinterpret_cast<unsigned*>(&Hs[i * HPAD_ + tid * 4]) = (unsigned)hv[i];
        }
        __syncthreads();

        // ---- z-tiles = h @ U (fp8 MFMA, K=1024, shared A-frag; local rows 0..15) ----
        f32x4 acc0 = {0,0,0,0}, acc1 = {0,0,0,0};
        #pragma unroll
        for (int ks = 0; ks < 32; ++ks) {
            u64 af = *reinterpret_cast<const u64*>(&Hs[lr * HPAD_ + ks * 32 + lq * 8]);
            acc0 = __builtin_amdgcn_mfma_f32_16x16x32_fp8_fp8((long)af, (long)ub0[ks], acc0, 0, 0, 0);
            acc1 = __builtin_amdgcn_mfma_f32_16x16x32_fp8_fp8((long)af, (long)ub1[ks], acc1, 0, 0, 0);
        }

        // ---- gates + merged pack/store per r ----
        const u64 tagw = (u64)(unsigned)(t + 1) << 32;
        const bool notlast = (t < S_ - 1);
        #pragma unroll
        for (int r = 0; r < 4; ++r) {
            bool mbk = (mask >> (m0 + lq * 4 + r)) & 1;
            {
                float z  = acc0[r] * (1.0f / 16384.0f) + bf2f((ushort)(xwv0 >> (16 * r)));
                float tg = tanh_fast(z);
                float x1 = __shfl_xor(tg, 1, 64);
                float x2 = __shfl_xor(tg, 2, 64);
                float x3 = __shfl_xor(tg, 3, 64);
                float tI = sel4(g,     tg, x1, x2, x3);
                float tF = sel4(g ^ 1, tg, x1, x2, x3);
                float tG = sel4(g ^ 2, tg, x1, x2, x3);
                float tO = sel4(g ^ 3, tg, x1, x2, x3);
                float cn = tF * creg0[r] + tI * tG;
                float hn = tO * tanh_fast(cn);
                if (mbk) { creg0[r] = cn; hreg0[r] = hn; }
            }
            {
                float z  = acc1[r] * (1.0f / 16384.0f) + bf2f((ushort)(xwv1 >> (16 * r)));
                float tg = tanh_fast(z);
                float x1 = __shfl_xor(tg, 1, 64);
                float x2 = __shfl_xor(tg, 2, 64);
                float x3 = __shfl_xor(tg, 3, 64);
                float tI = sel4(g,     tg, x1, x2, x3);
                float tF = sel4(g ^ 1, tg, x1, x2, x3);
                float tG = sel4(g ^ 2, tg, x1, x2, x3);
                float tO = sel4(g ^ 3, tg, x1, x2, x3);
                float cn = tF * creg1[r] + tI * tG;
                float hn = tO * tanh_fast(cn);
                if (mbk) { creg1[r] = cn; hreg1[r] = hn; }
            }
            if (notlast) {
                float a0 = hreg0[r] * 256.0f;
                float b0 = __shfl_xor(a0, 4, 64);
                float cc0 = __shfl_xor(a0, 8, 64);
                float d0 = __shfl_xor(a0, 12, 64);
                int pk0 = __builtin_amdgcn_cvt_pk_fp8_f32(a0, b0, 0, false);
                pk0     = __builtin_amdgcn_cvt_pk_fp8_f32(cc0, d0, pk0, true);
                float a1 = hreg1[r] * 256.0f;
                float b1 = __shfl_xor(a1, 4, 64);
                float cc1 = __shfl_xor(a1, 8, 64);
                float d1 = __shfl_xor(a1, 12, 64);
                int pk1 = __builtin_amdgcn_cvt_pk_fp8_f32(a1, b1, 0, false);
                pk1     = __builtin_amdgcn_cvt_pk_fp8_f32(cc1, d1, pk1, true);
                if (lr == 0) {
                    int row = m0 + lq * 4 + r;
                    __hip_atomic_store(hnxt + (size_t)row * 256 + cb,     (u64)(unsigned)pk0 | tagw,
                                       __ATOMIC_RELAXED, __HIP_MEMORY_SCOPE_AGENT);
                    __hip_atomic_store(hnxt + (size_t)row * 256 + cb + 1, (u64)(unsigned)pk1 | tagw,
                                       __ATOMIC_RELAXED, __HIP_MEMORY_SCOPE_AGENT);
                }
            }
        }

        if (notlast) {
            // ---- gate xw prefetch on gemm completion (pipelined: register compare) ----
            int mbn = (t + 1) >> 1;
            if (mbn >= mb_conf) {
                while (cv < 32u) {
                    __builtin_amdgcn_s_sleep(4);
                    cv = __hip_atomic_load(&cnt[mbn], __ATOMIC_RELAXED, __HIP_MEMORY_SCOPE_AGENT);
                }
                mb_conf = mbn + 1;
                int nx = mbn + 1 < 256 ? mbn + 1 : 255;
                cv = __hip_atomic_load(&cnt[nx], __ATOMIC_RELAXED, __HIP_MEMORY_SCOPE_AGENT);
                asm volatile("" ::: "memory");
            }
            xwv0 = *reinterpret_cast<const u64*>(xWT + ((size_t)(t + 1) * G4_ + c0) * B_ + m0 + lq * 4);
            xwv1 = *reinterpret_cast<const u64*>(xWT + ((size_t)(t + 1) * G4_ + c1) * B_ + m0 + lq * 4);
            mask = m32[t + 1];
            const u64* tsw = hcur; hcur = hnxt; hnxt = (u64*)tsw;
        } else {
            // ---- final: write (h, h, c) fp32 ----
            if (g == 0) {
                int j0 = c0 >> 2, j1 = c1 >> 2;
                #pragma unroll
                for (int r = 0; r < 4; ++r) {
                    int row = m0 + lq * 4 + r;
                    out[row * H_ + j0]               = hreg0[r];
                    out[B_ * H_ + row * H_ + j0]     = hreg0[r];
                    out[2 * B_ * H_ + row * H_ + j0] = creg0[r];
                    out[row * H_ + j1]               = hreg1[r];
                    out[B_ * H_ + row * H_ + j1]     = hreg1[r];
                    out[2 * B_ * H_ + row * H_ + j1] = creg1[r];
                }
            }
        }
    }
}

extern "C" void kernel_launch(void* const* d_in, const int* in_sizes, int n_in,
                              void* d_out, int out_size, void* d_ws, size_t ws_size,
                              hipStream_t stream) {
    (void)in_sizes; (void)n_in; (void)out_size; (void)ws_size;
    const int*   tokens = (const int*)  d_in[0];
    const float* emb    = (const float*)d_in[1];
    const float* W      = (const float*)d_in[2];
    const float* U      = (const float*)d_in[3];
    const float* bias   = (const float*)d_in[4];

    char* ws = (char*)d_ws;
    ushort*        WT   = (ushort*)ws;                               // 4 MB
    unsigned char* UT   = (unsigned char*)(ws + (4u << 20));         // 4 MB fp8
    ushort*        xWT  = (ushort*)(ws + (8u << 20));                // 128 MB
    u64*           hA   = (u64*)(ws + (136u << 20));                 // 64 KB tagged
    u64*           hB   = hA + 8192;                                 // 64 KB tagged
    unsigned*      m32  = (unsigned*)(hB + 8192);                    // 2 KB
    unsigned*      cnt  = m32 + 512;                                 // 1 KB

    init_kernel<<<16, 256, 0, stream>>>(tokens, hA, cnt, m32);
    transpose_w_kernel<<<dim3(G4_ / 32, E_ / 32), 256, 0, stream>>>(W, WT);
    transpose_u_kernel<<<dim3(G4_ / 32, H_ / 32), 256, 0, stream>>>(U, (unsigned*)UT);
    mono_kernel<<<NSB_ + NGB_, 256, 0, stream>>>(UT, xWT, m32, hA, hB, cnt, (float*)d_out,
                                                 tokens, emb, WT, bias);
}